// Round 7
// baseline (1393.029 us; speedup 1.0000x reference)
//
#include <hip/hip_runtime.h>

#define B_ 256
#define S_ 512
#define V_ 50000
#define F_ 64
#define H_ 256

typedef _Float16 f16;
typedef _Float16 f16x2 __attribute__((ext_vector_type(2)));
typedef _Float16 f16x4 __attribute__((ext_vector_type(4)));
typedef _Float16 f16x8 __attribute__((ext_vector_type(8)));
typedef float f32x4 __attribute__((ext_vector_type(4)));

#define MFMA(a, b, c) __builtin_amdgcn_mfma_f32_16x16x32_f16((a), (b), (c), 0, 0, 0)

__device__ __forceinline__ f16x8 cvt8(const float4 a, const float4 b) {
    f16x8 v;
    v[0] = (f16)a.x; v[1] = (f16)a.y; v[2] = (f16)a.z; v[3] = (f16)a.w;
    v[4] = (f16)b.x; v[5] = (f16)b.y; v[6] = (f16)b.z; v[7] = (f16)b.w;
    return v;
}

// tanh(x) = 1 - 2/(1+e^2x); IEEE-safe at +/-inf.
__device__ __forceinline__ float fast_tanh(float x) {
    float e = __expf(2.f * x);
    float r = __builtin_amdgcn_rcpf(e + 1.f);
    return __builtin_fmaf(-2.f, r, 1.f);
}

__device__ __forceinline__ f32x4 cvt4f(const f16x4 v) {
    f32x4 r; r[0] = (float)v[0]; r[1] = (float)v[1]; r[2] = (float)v[2]; r[3] = (float)v[3];
    return r;
}
__device__ __forceinline__ f16x4 pack4(const f32x4 v) {
    f16x4 r; r[0] = (f16)v[0]; r[1] = (f16)v[1]; r[2] = (f16)v[2]; r[3] = (f16)v[3];
    return r;
}
__device__ __forceinline__ f16x4 tanh4(const f32x4 v) {
    f16x4 r;
#pragma unroll
    for (int i = 0; i < 4; ++i) r[i] = (f16)fast_tanh(v[i]);
    return r;
}

// ---------------------------------------------------------------------------
// K0: zero the producer->consumer flags (every launch/replay).
// ---------------------------------------------------------------------------
__global__ void k_init_flags(int* flags) {
    if (threadIdx.x < 128) flags[threadIdx.x] = 0;
}

// ---------------------------------------------------------------------------
// K1: T[v][n] = sum_f feat[v][f] * Wih0[n][f] + (bih0[n]+bhh0[n]); f16 out.
// ---------------------------------------------------------------------------
__global__ __launch_bounds__(512) void k_vocab_proj(
    const float* __restrict__ feat, const float* __restrict__ Wih,
    const float* __restrict__ bi, const float* __restrict__ bh,
    f16* __restrict__ T)
{
    __shared__ char Wl[256 * 128];
    __shared__ char Xl[16 * 128];
    const int tid = threadIdx.x;
    {
        const int n = tid >> 1, k0 = (tid & 1) << 5;
#pragma unroll
        for (int k = k0; k < k0 + 32; k += 8) {
            float4 a = *(const float4*)(Wih + n * F_ + k);
            float4 b = *(const float4*)(Wih + n * F_ + k + 4);
            *(f16x8*)(Wl + n * 128 + (((k >> 3) ^ (n & 7)) << 4)) = cvt8(a, b);
        }
    }
    const int v0 = blockIdx.x * 16;
    {
        const int m = tid >> 5, k = (tid & 31) << 1;
        float2 a = *(const float2*)(feat + (v0 + m) * F_ + k);
        f16x2 v; v[0] = (f16)a.x; v[1] = (f16)a.y;
        *(f16x2*)(Xl + m * 128 + ((((k >> 3) ^ (m & 7)) << 4) | ((k & 7) << 1))) = v;
    }
    __syncthreads();
    const int lane = tid & 63, w = tid >> 6;
    const int q = lane & 15, g = lane >> 4;
#pragma unroll
    for (int nt = 0; nt < 2; ++nt) {
        const int n0 = w * 32 + nt * 16;
        const int nrow = n0 + q;
        float4 b1 = *(const float4*)(bi + n0 + g * 4);
        float4 b2 = *(const float4*)(bh + n0 + g * 4);
        f32x4 acc = {b1.x + b2.x, b1.y + b2.y, b1.z + b2.z, b1.w + b2.w};
#pragma unroll
        for (int kb = 0; kb < 2; ++kb) {
            f16x8 a = *(const f16x8*)(Wl + nrow * 128 + (((kb * 4 + g) ^ (nrow & 7)) << 4));
            f16x8 b = *(const f16x8*)(Xl + q * 128 + (((kb * 4 + g) ^ (q & 7)) << 4));
            acc = MFMA(a, b, acc);
        }
        f16x4 o; o[0] = (f16)acc[0]; o[1] = (f16)acc[1]; o[2] = (f16)acc[2]; o[3] = (f16)acc[3];
        *(f16x4*)(T + (size_t)(v0 + q) * H_ + n0 + g * 4) = o;
    }
}

// ---------------------------------------------------------------------------
// K2: split-layer persistent RNN. 16 WGs x 512 thr, 32 batch rows per WG
// (2 m-tiles -> 2x independent MFMA chains; wall time = 512 x step-latency,
// so amortize the latency over 2x rows).
//   WGs 0-7  (producer p): layer-0 recurrence + layer-1 input projection
//     p_t = b1 + Wih1 @ h0_t  -> pbuf (f16). Flag released every 8 steps.
//   WGs 8-15 (consumer, pair p=wg-8): layer-1 recurrence, lagging ~8 steps.
// NO register pin (R5/R6 errata: "+v" forces arch-VGPRs, evicting weights
// from AGPRs -> spills; MFMA reads A/B from AGPR natively, VGPR_Count does
// not show AGPRs). All LDS addresses hoisted to registers; buffer parity and
// kb are compile-time offset immediates.
// ---------------------------------------------------------------------------
__global__ __launch_bounds__(512) __attribute__((amdgpu_waves_per_eu(2, 2)))
void k_rnn_split(
    const f16* __restrict__ T, const int* __restrict__ idx,
    const float* __restrict__ Whh0, const float* __restrict__ Wih1,
    const float* __restrict__ bih1, const float* __restrict__ bhh1,
    const float* __restrict__ Whh1,
    f16* __restrict__ pbuf, int* flags, f16* __restrict__ h1out)
{
    __shared__ char hb[32768];   // [2 buf][32 rows][256 f16], XOR-swizzled
    const int wg = blockIdx.x;
    const int tid = threadIdx.x, lane = tid & 63, w = tid >> 6;
    const int q = lane & 15, g = lane >> 4;
    const int ncol = w * 32;
    const int swz = (q & 7) << 4;

    // loop-invariant LDS addresses (read: per m x kb-parity; write: per m x tt)
    int rbase[2][2], wbase[2][2];
#pragma unroll
    for (int m = 0; m < 2; ++m) {
#pragma unroll
        for (int p2 = 0; p2 < 2; ++p2)
            rbase[m][p2] = (q + m * 16) * 512 + ((p2 * 64 + g * 16) ^ swz);
#pragma unroll
        for (int tt = 0; tt < 2; ++tt)
            wbase[m][tt] = (q + m * 16) * 512 + (((ncol + tt * 16 + g * 4) * 2) ^ swz);
    }
    const int pr = (wg < 8) ? wg : wg - 8;
    const int brow0 = pr * 32 + q, brow1 = brow0 + 16;
    const size_t prow0 = (size_t)brow0 * 512, prow1 = (size_t)brow1 * 512;

#define FRD(m_, kb_, RD_) (*(const f16x8*)(hb + (RD_) * 16384 + rbase[m_][(kb_) & 1] + (((kb_) >> 1) * 128)))
#define HWR(m_, tt_, WR_) (*(f16x4*)(hb + (WR_) * 16384 + wbase[m_][tt_]))
#define STEP_BAR() do { \
        asm volatile("s_waitcnt lgkmcnt(0)" ::: "memory"); \
        __builtin_amdgcn_s_barrier(); \
    } while (0)

    if (wg < 8) {
        // ================= PRODUCER =================
        f16x8 wA[2][8], wP[2][8];
#pragma unroll
        for (int tt = 0; tt < 2; ++tt) {
            const int n = ncol + tt * 16 + q;
#pragma unroll
            for (int kb = 0; kb < 8; ++kb) {
                const int o = n * H_ + kb * 32 + g * 8;
                wA[tt][kb] = cvt8(*(const float4*)(Whh0 + o), *(const float4*)(Whh0 + o + 4));
                wP[tt][kb] = cvt8(*(const float4*)(Wih1 + o), *(const float4*)(Wih1 + o + 4));
            }
        }
        f32x4 bs1[2];
#pragma unroll
        for (int tt = 0; tt < 2; ++tt) {
            const int n = ncol + tt * 16 + g * 4;
            float4 x = *(const float4*)(bih1 + n);
            float4 y = *(const float4*)(bhh1 + n);
            bs1[tt][0] = x.x + y.x; bs1[tt][1] = x.y + y.y;
            bs1[tt][2] = x.z + y.z; bs1[tt][3] = x.w + y.w;
        }
        {   // h0_{-1}=0 into buf1 (read buffer of step 0): 512 thr x 32B = 16KB
            f32x4 z = {0.f, 0.f, 0.f, 0.f};
            *(f32x4*)(hb + 16384 + tid * 32) = z;
            *(f32x4*)(hb + 16384 + tid * 32 + 16) = z;
        }
        const int* idxr0 = idx + brow0 * S_;
        const int* idxr1 = idx + brow1 * S_;
        int* myflag = flags + wg * 8 + w;
        f16x4 xa[2][2], xb[2][2];
        {
            const size_t ra0 = (size_t)idxr0[0] * H_, ra1 = (size_t)idxr1[0] * H_;
            const size_t rb0 = (size_t)idxr0[1] * H_, rb1 = (size_t)idxr1[1] * H_;
#pragma unroll
            for (int tt = 0; tt < 2; ++tt) {
                xa[0][tt] = *(const f16x4*)(T + ra0 + ncol + tt * 16 + g * 4);
                xa[1][tt] = *(const f16x4*)(T + ra1 + ncol + tt * 16 + g * 4);
                xb[0][tt] = *(const f16x4*)(T + rb0 + ncol + tt * 16 + g * 4);
                xb[1][tt] = *(const f16x4*)(T + rb1 + ncol + tt * 16 + g * 4);
            }
        }
        int iA0 = idxr0[2], iA1 = idxr1[2], iB0 = idxr0[3], iB1 = idxr1[3];
        __syncthreads();

#define PBODY(XV, I0, I1, RD, WR, T_) do {                                      \
        f32x4 aA[2][2], aP[2][2];                                               \
        _Pragma("unroll")                                                       \
        for (int m = 0; m < 2; ++m)                                             \
            _Pragma("unroll")                                                   \
            for (int tt = 0; tt < 2; ++tt) {                                    \
                aA[m][tt] = cvt4f(XV[m][tt]); aP[m][tt] = bs1[tt];              \
            }                                                                   \
        {   /* reissue XV <- rows (T_+2); reload ids <- idx[T_+4] */            \
            const size_t r0 = (size_t)(I0) * H_, r1 = (size_t)(I1) * H_;        \
            _Pragma("unroll")                                                   \
            for (int tt = 0; tt < 2; ++tt) {                                    \
                XV[0][tt] = *(const f16x4*)(T + r0 + ncol + tt * 16 + g * 4);   \
                XV[1][tt] = *(const f16x4*)(T + r1 + ncol + tt * 16 + g * 4);   \
            }                                                                   \
            const int t4 = ((T_) + 4 < S_) ? (T_) + 4 : S_ - 1;                 \
            I0 = idxr0[t4]; I1 = idxr1[t4];                                     \
        }                                                                       \
        _Pragma("unroll")                                                       \
        for (int kb = 0; kb < 8; ++kb) {                                        \
            f16x8 b0 = FRD(0, kb, RD), b1 = FRD(1, kb, RD);                     \
            _Pragma("unroll")                                                   \
            for (int tt = 0; tt < 2; ++tt) {                                    \
                aA[0][tt] = MFMA(wA[tt][kb], b0, aA[0][tt]);                    \
                aA[1][tt] = MFMA(wA[tt][kb], b1, aA[1][tt]);                    \
                aP[0][tt] = MFMA(wP[tt][kb], b0, aP[0][tt]);                    \
                aP[1][tt] = MFMA(wP[tt][kb], b1, aP[1][tt]);                    \
            }                                                                   \
        }                                                                       \
        _Pragma("unroll")                                                       \
        for (int tt = 0; tt < 2; ++tt) {                                        \
            HWR(0, tt, WR) = tanh4(aA[0][tt]);                                  \
            HWR(1, tt, WR) = tanh4(aA[1][tt]);                                  \
            *(f16x4*)(pbuf + (prow0 + (T_) - 1) * 256 + ncol + tt * 16 + g * 4) = pack4(aP[0][tt]); \
            *(f16x4*)(pbuf + (prow1 + (T_) - 1) * 256 + ncol + tt * 16 + g * 4) = pack4(aP[1][tt]); \
        }                                                                       \
        if ((((T_) & 7) == 0) && lane == 0)                                     \
            __hip_atomic_store(myflag, (T_), __ATOMIC_RELEASE,                  \
                               __HIP_MEMORY_SCOPE_AGENT);                       \
        STEP_BAR();                                                             \
    } while (0)

        // peel t=0: A-chain only (h0_0 from zeros in buf1), reissue xa <- x_2
        {
            f32x4 aA[2][2];
#pragma unroll
            for (int m = 0; m < 2; ++m)
#pragma unroll
                for (int tt = 0; tt < 2; ++tt) aA[m][tt] = cvt4f(xa[m][tt]);
            {
                const size_t r0 = (size_t)iA0 * H_, r1 = (size_t)iA1 * H_;
#pragma unroll
                for (int tt = 0; tt < 2; ++tt) {
                    xa[0][tt] = *(const f16x4*)(T + r0 + ncol + tt * 16 + g * 4);
                    xa[1][tt] = *(const f16x4*)(T + r1 + ncol + tt * 16 + g * 4);
                }
                iA0 = idxr0[4]; iA1 = idxr1[4];
            }
#pragma unroll
            for (int kb = 0; kb < 8; ++kb) {
                f16x8 b0 = FRD(0, kb, 1), b1 = FRD(1, kb, 1);
#pragma unroll
                for (int tt = 0; tt < 2; ++tt) {
                    aA[0][tt] = MFMA(wA[tt][kb], b0, aA[0][tt]);
                    aA[1][tt] = MFMA(wA[tt][kb], b1, aA[1][tt]);
                }
            }
#pragma unroll
            for (int tt = 0; tt < 2; ++tt) {
                HWR(0, tt, 0) = tanh4(aA[0][tt]);
                HWR(1, tt, 0) = tanh4(aA[1][tt]);
            }
            STEP_BAR();
        }
        // main: T_ = 1..510 in parity pairs, then 511
        for (int t = 1; t < 511; t += 2) {
            PBODY(xb, iB0, iB1, 0, 1, t);
            PBODY(xa, iA0, iA1, 1, 0, t + 1);
        }
        PBODY(xb, iB0, iB1, 0, 1, 511);
        // peel T_=512: p_511 from h0_511 (in buf1)
        {
            f32x4 aP[2][2];
#pragma unroll
            for (int m = 0; m < 2; ++m)
#pragma unroll
                for (int tt = 0; tt < 2; ++tt) aP[m][tt] = bs1[tt];
#pragma unroll
            for (int kb = 0; kb < 8; ++kb) {
                f16x8 b0 = FRD(0, kb, 1), b1 = FRD(1, kb, 1);
#pragma unroll
                for (int tt = 0; tt < 2; ++tt) {
                    aP[0][tt] = MFMA(wP[tt][kb], b0, aP[0][tt]);
                    aP[1][tt] = MFMA(wP[tt][kb], b1, aP[1][tt]);
                }
            }
#pragma unroll
            for (int tt = 0; tt < 2; ++tt) {
                *(f16x4*)(pbuf + (prow0 + 511) * 256 + ncol + tt * 16 + g * 4) = pack4(aP[0][tt]);
                *(f16x4*)(pbuf + (prow1 + 511) * 256 + ncol + tt * 16 + g * 4) = pack4(aP[1][tt]);
            }
        }
        if (lane == 0)
            __hip_atomic_store(myflag, 512, __ATOMIC_RELEASE, __HIP_MEMORY_SCOPE_AGENT);
#undef PBODY
    } else {
        // ================= CONSUMER =================
        f16x8 wC[2][8];
#pragma unroll
        for (int tt = 0; tt < 2; ++tt) {
            const int n = ncol + tt * 16 + q;
#pragma unroll
            for (int kb = 0; kb < 8; ++kb) {
                const int o = n * H_ + kb * 32 + g * 8;
                wC[tt][kb] = cvt8(*(const float4*)(Whh1 + o), *(const float4*)(Whh1 + o + 4));
            }
        }
        {   // h1_{-1}=0 into buf1
            f32x4 z = {0.f, 0.f, 0.f, 0.f};
            *(f32x4*)(hb + 16384 + tid * 32) = z;
            *(f32x4*)(hb + 16384 + tid * 32 + 16) = z;
        }
        const int* fl = flags + pr * 8;
        __syncthreads();

#define SPIN(need) do {                                                         \
        int mn;                                                                 \
        do {                                                                    \
            mn = 0x7fffffff;                                                    \
            _Pragma("unroll")                                                   \
            for (int i = 0; i < 8; ++i) {                                       \
                int v = __hip_atomic_load(fl + i, __ATOMIC_RELAXED,             \
                                          __HIP_MEMORY_SCOPE_AGENT);            \
                mn = v < mn ? v : mn;                                           \
            }                                                                   \
        } while (mn < (need));                                                  \
        __builtin_amdgcn_fence(__ATOMIC_ACQUIRE, "agent");                      \
    } while (0)

#define CBODY(PV, RD, WR, T_) do {                                              \
        f32x4 aC[2][2];                                                         \
        _Pragma("unroll")                                                       \
        for (int m = 0; m < 2; ++m)                                             \
            _Pragma("unroll")                                                   \
            for (int tt = 0; tt < 2; ++tt) aC[m][tt] = cvt4f(PV[m][tt]);        \
        {                                                                       \
            const int tr = ((T_) + 2 < S_) ? (T_) + 2 : S_ - 1;                 \
            _Pragma("unroll")                                                   \
            for (int tt = 0; tt < 2; ++tt) {                                    \
                PV[0][tt] = *(const f16x4*)(pbuf + (prow0 + tr) * 256 + ncol + tt * 16 + g * 4); \
                PV[1][tt] = *(const f16x4*)(pbuf + (prow1 + tr) * 256 + ncol + tt * 16 + g * 4); \
            }                                                                   \
        }                                                                       \
        _Pragma("unroll")                                                       \
        for (int kb = 0; kb < 8; ++kb) {                                        \
            f16x8 b0 = FRD(0, kb, RD), b1 = FRD(1, kb, RD);                     \
            _Pragma("unroll")                                                   \
            for (int tt = 0; tt < 2; ++tt) {                                    \
                aC[0][tt] = MFMA(wC[tt][kb], b0, aC[0][tt]);                    \
                aC[1][tt] = MFMA(wC[tt][kb], b1, aC[1][tt]);                    \
            }                                                                   \
        }                                                                       \
        _Pragma("unroll")                                                       \
        for (int tt = 0; tt < 2; ++tt) {                                        \
            f16x4 h0v = tanh4(aC[0][tt]), h1v = tanh4(aC[1][tt]);               \
            HWR(0, tt, WR) = h0v;                                               \
            HWR(1, tt, WR) = h1v;                                               \
            if ((T_) == S_ - 1) {                                               \
                *(f16x4*)(h1out + (size_t)brow0 * H_ + ncol + tt * 16 + g * 4) = h0v; \
                *(f16x4*)(h1out + (size_t)brow1 * H_ + ncol + tt * 16 + g * 4) = h1v; \
            }                                                                   \
        }                                                                       \
        STEP_BAR();                                                             \
    } while (0)

        f16x4 pa[2][2], pb[2][2];
        SPIN(6);
#pragma unroll
        for (int tt = 0; tt < 2; ++tt) {
            pa[0][tt] = *(const f16x4*)(pbuf + (prow0 + 0) * 256 + ncol + tt * 16 + g * 4);
            pa[1][tt] = *(const f16x4*)(pbuf + (prow1 + 0) * 256 + ncol + tt * 16 + g * 4);
            pb[0][tt] = *(const f16x4*)(pbuf + (prow0 + 1) * 256 + ncol + tt * 16 + g * 4);
            pb[1][tt] = *(const f16x4*)(pbuf + (prow1 + 1) * 256 + ncol + tt * 16 + g * 4);
        }
        for (int tb = 0; tb < 512; tb += 4) {
            if (tb) {
                const int need = (tb + 6 < 512) ? tb + 6 : 512;
                SPIN(need);
            }
            CBODY(pa, 1, 0, tb);
            CBODY(pb, 0, 1, tb + 1);
            CBODY(pa, 1, 0, tb + 2);
            CBODY(pb, 0, 1, tb + 3);
        }
#undef CBODY
#undef SPIN
    }
#undef FRD
#undef HWR
#undef STEP_BAR
}

// ---------------------------------------------------------------------------
// K3: out[b][v] = sum_k h1[b][k] * Wout[v][k] + bout[v].  fp32 out.
// ---------------------------------------------------------------------------
__global__ __launch_bounds__(512) void k_out(
    const f16* __restrict__ h1, const float* __restrict__ Wout,
    const float* __restrict__ bout, float* __restrict__ out)
{
    __shared__ char Hl[256 * 512];
    const int tid = threadIdx.x;
    {
        const int m = tid >> 1, half = tid & 1;
#pragma unroll
        for (int i = 0; i < 16; ++i) {
            const int blk = half * 16 + i;
            f16x8 v = *(const f16x8*)(h1 + m * H_ + blk * 8);
            *(f16x8*)(Hl + m * 512 + ((blk ^ (m & 7)) << 4)) = v;
        }
    }
    __syncthreads();
    const int lane = tid & 63, w = tid >> 6;
    const int q = lane & 15, g = lane >> 4;
    const int v0 = blockIdx.x * 80;
    f32x4 acc[5][2];
#pragma unroll
    for (int vt = 0; vt < 5; ++vt) {
        float4 bo = *(const float4*)(bout + v0 + vt * 16 + g * 4);
#pragma unroll
        for (int bt = 0; bt < 2; ++bt) {
            acc[vt][bt][0] = bo.x; acc[vt][bt][1] = bo.y;
            acc[vt][bt][2] = bo.z; acc[vt][bt][3] = bo.w;
        }
    }
#pragma unroll
    for (int kb = 0; kb < 8; ++kb) {
        f16x8 bf[2];
#pragma unroll
        for (int bt = 0; bt < 2; ++bt) {
            const int mrow = (w * 2 + bt) * 16 + q;
            bf[bt] = *(const f16x8*)(Hl + mrow * 512 + (((kb * 4 + g) ^ (mrow & 7)) << 4));
        }
#pragma unroll
        for (int vt = 0; vt < 5; ++vt) {
            const size_t vrow = v0 + vt * 16 + q;
            float4 a = *(const float4*)(Wout + vrow * H_ + kb * 32 + g * 8);
            float4 b = *(const float4*)(Wout + vrow * H_ + kb * 32 + g * 8 + 4);
            f16x8 af = cvt8(a, b);
#pragma unroll
            for (int bt = 0; bt < 2; ++bt)
                acc[vt][bt] = MFMA(af, bf[bt], acc[vt][bt]);
        }
    }
#pragma unroll
    for (int vt = 0; vt < 5; ++vt)
#pragma unroll
        for (int bt = 0; bt < 2; ++bt) {
            const int b = (w * 2 + bt) * 16 + q;
            const int v = v0 + vt * 16 + g * 4;
            float4 o = {acc[vt][bt][0], acc[vt][bt][1], acc[vt][bt][2], acc[vt][bt][3]};
            *(float4*)(out + (size_t)b * V_ + v) = o;
        }
}

extern "C" void kernel_launch(void* const* d_in, const int* in_sizes, int n_in,
                              void* d_out, int out_size, void* d_ws, size_t ws_size,
                              hipStream_t stream) {
    (void)in_sizes; (void)n_in; (void)out_size; (void)ws_size;
    const int*   batch = (const int*)  d_in[0];
    const float* feat  = (const float*)d_in[1];
    const float* Wih0  = (const float*)d_in[2];
    const float* Whh0  = (const float*)d_in[3];
    const float* bih0  = (const float*)d_in[4];
    const float* bhh0  = (const float*)d_in[5];
    const float* Wih1  = (const float*)d_in[6];
    const float* Whh1  = (const float*)d_in[7];
    const float* bih1  = (const float*)d_in[8];
    const float* bhh1  = (const float*)d_in[9];
    const float* Wout  = (const float*)d_in[10];
    const float* bout  = (const float*)d_in[11];
    float* out = (float*)d_out;

    f16* T     = (f16*)d_out;                             // 25.6MB scratch in d_out
    int* flags = (int*)((char*)d_out + 48000000);         // 512B, dead until k_out
    f16* pbuf  = (f16*)d_ws;                              // 67MB: p_t stream
    f16* h1out = (f16*)((char*)d_ws + (size_t)B_ * S_ * H_ * 2);  // 128KB

    k_init_flags<<<dim3(1), dim3(128), 0, stream>>>(flags);
    k_vocab_proj<<<dim3(V_ / 16), dim3(512), 0, stream>>>(feat, Wih0, bih0, bhh0, T);
    k_rnn_split<<<dim3(16), dim3(512), 0, stream>>>(T, batch, Whh0, Wih1, bih1, bhh1,
                                                    Whh1, pbuf, flags, h1out);
    k_out<<<dim3(625), dim3(512), 0, stream>>>(h1out, Wout, bout, out);
}

// Round 8
// 934.538 us; speedup vs baseline: 1.4906x; 1.4906x over previous
//
#include <hip/hip_runtime.h>

#define B_ 256
#define S_ 512
#define V_ 50000
#define F_ 64
#define H_ 256

typedef _Float16 f16;
typedef _Float16 f16x2 __attribute__((ext_vector_type(2)));
typedef _Float16 f16x4 __attribute__((ext_vector_type(4)));
typedef _Float16 f16x8 __attribute__((ext_vector_type(8)));
typedef float f32x4 __attribute__((ext_vector_type(4)));

#define MFMA(a, b, c) __builtin_amdgcn_mfma_f32_16x16x32_f16((a), (b), (c), 0, 0, 0)

__device__ __forceinline__ f16x8 cvt8(const float4 a, const float4 b) {
    f16x8 v;
    v[0] = (f16)a.x; v[1] = (f16)a.y; v[2] = (f16)a.z; v[3] = (f16)a.w;
    v[4] = (f16)b.x; v[5] = (f16)b.y; v[6] = (f16)b.z; v[7] = (f16)b.w;
    return v;
}

// tanh(x) = 1 - 2/(1+e^2x); IEEE-safe at +/-inf.
__device__ __forceinline__ float fast_tanh(float x) {
    float e = __expf(2.f * x);
    float r = __builtin_amdgcn_rcpf(e + 1.f);
    return __builtin_fmaf(-2.f, r, 1.f);
}

__device__ __forceinline__ f32x4 cvt4f(const f16x4 v) {
    f32x4 r; r[0] = (float)v[0]; r[1] = (float)v[1]; r[2] = (float)v[2]; r[3] = (float)v[3];
    return r;
}
__device__ __forceinline__ f16x4 pack4(const f32x4 a, const f32x4 b) {
    f16x4 r; r[0] = (f16)(a[0] + b[0]); r[1] = (f16)(a[1] + b[1]);
    r[2] = (f16)(a[2] + b[2]); r[3] = (f16)(a[3] + b[3]);
    return r;
}
__device__ __forceinline__ f16x4 tanh4(const f32x4 a, const f32x4 b) {
    f16x4 r;
#pragma unroll
    for (int i = 0; i < 4; ++i) r[i] = (f16)fast_tanh(a[i] + b[i]);
    return r;
}

// ---------------------------------------------------------------------------
// K0: zero the producer->consumer flags (every launch/replay).
// ---------------------------------------------------------------------------
__global__ void k_init_flags(int* flags) {
    if (threadIdx.x < 128) flags[threadIdx.x] = 0;
}

// ---------------------------------------------------------------------------
// K1: T[v][n] = sum_f feat[v][f] * Wih0[n][f] + (bih0[n]+bhh0[n]); f16 out.
// ---------------------------------------------------------------------------
__global__ __launch_bounds__(512) void k_vocab_proj(
    const float* __restrict__ feat, const float* __restrict__ Wih,
    const float* __restrict__ bi, const float* __restrict__ bh,
    f16* __restrict__ T)
{
    __shared__ char Wl[256 * 128];
    __shared__ char Xl[16 * 128];
    const int tid = threadIdx.x;
    {
        const int n = tid >> 1, k0 = (tid & 1) << 5;
#pragma unroll
        for (int k = k0; k < k0 + 32; k += 8) {
            float4 a = *(const float4*)(Wih + n * F_ + k);
            float4 b = *(const float4*)(Wih + n * F_ + k + 4);
            *(f16x8*)(Wl + n * 128 + (((k >> 3) ^ (n & 7)) << 4)) = cvt8(a, b);
        }
    }
    const int v0 = blockIdx.x * 16;
    {
        const int m = tid >> 5, k = (tid & 31) << 1;
        float2 a = *(const float2*)(feat + (v0 + m) * F_ + k);
        f16x2 v; v[0] = (f16)a.x; v[1] = (f16)a.y;
        *(f16x2*)(Xl + m * 128 + ((((k >> 3) ^ (m & 7)) << 4) | ((k & 7) << 1))) = v;
    }
    __syncthreads();
    const int lane = tid & 63, w = tid >> 6;
    const int q = lane & 15, g = lane >> 4;
#pragma unroll
    for (int nt = 0; nt < 2; ++nt) {
        const int n0 = w * 32 + nt * 16;
        const int nrow = n0 + q;
        float4 b1 = *(const float4*)(bi + n0 + g * 4);
        float4 b2 = *(const float4*)(bh + n0 + g * 4);
        f32x4 acc = {b1.x + b2.x, b1.y + b2.y, b1.z + b2.z, b1.w + b2.w};
#pragma unroll
        for (int kb = 0; kb < 2; ++kb) {
            f16x8 a = *(const f16x8*)(Wl + nrow * 128 + (((kb * 4 + g) ^ (nrow & 7)) << 4));
            f16x8 b = *(const f16x8*)(Xl + q * 128 + (((kb * 4 + g) ^ (q & 7)) << 4));
            acc = MFMA(a, b, acc);
        }
        f16x4 o; o[0] = (f16)acc[0]; o[1] = (f16)acc[1]; o[2] = (f16)acc[2]; o[3] = (f16)acc[3];
        *(f16x4*)(T + (size_t)(v0 + q) * H_ + n0 + g * 4) = o;
    }
}

// ---------------------------------------------------------------------------
// K2: split-layer persistent RNN. 32 WGs x 512 thr, 16 batch rows per WG.
//   WGs 0-15  (producer p): layer-0 recurrence; P-projection
//     p_t = b1 + Wih1 @ h0_t -> pbuf runs AFTER the h0 ds_write, off the
//     inter-barrier critical path (pure register work on live B-fragments).
//   WGs 16-31 (consumer, pair wg-16): layer-1 recurrence, lagging ~8 steps.
// All MFMA chains kb-split to 4-deep. No register pin (R5/R6 errata: "+v"
// forces arch VGPRs, evicting weights from AGPRs -> spills). LDS addresses
// hoisted; buffer parity and kb are compile-time offsets.
// ---------------------------------------------------------------------------
__global__ __launch_bounds__(512) __attribute__((amdgpu_waves_per_eu(2, 2)))
void k_rnn_split(
    const f16* __restrict__ T, const int* __restrict__ idx,
    const float* __restrict__ Whh0, const float* __restrict__ Wih1,
    const float* __restrict__ bih1, const float* __restrict__ bhh1,
    const float* __restrict__ Whh1,
    f16* __restrict__ pbuf, int* flags, f16* __restrict__ h1out)
{
    __shared__ char hb[2][8192];   // double-buffered [16 rows][256 f16], swizzled
    const int wg = blockIdx.x;
    const int tid = threadIdx.x, lane = tid & 63, w = tid >> 6;
    const int q = lane & 15, g = lane >> 4;
    const int ncol = w * 32;
    const int swz = (q & 7) << 4;

    // loop-invariant LDS addresses (read: per kb-parity; write: per tt)
    int rbase[2], wbase[2];
#pragma unroll
    for (int p2 = 0; p2 < 2; ++p2)
        rbase[p2] = q * 512 + ((p2 * 64 + g * 16) ^ swz);
#pragma unroll
    for (int tt = 0; tt < 2; ++tt)
        wbase[tt] = q * 512 + (((ncol + tt * 16 + g * 4) * 2) ^ swz);

    const int pr = (wg < 16) ? wg : wg - 16;
    const int brow = pr * 16 + q;
    const size_t prow = (size_t)brow * 512;

#define FRD(kb_, RD_) (*(const f16x8*)(hb[RD_] + rbase[(kb_) & 1] + (((kb_) >> 1) * 128)))
#define HWR(tt_, WR_) (*(f16x4*)(hb[WR_] + wbase[tt_]))
#define STEP_BAR() do { \
        asm volatile("s_waitcnt lgkmcnt(0)" ::: "memory"); \
        __builtin_amdgcn_s_barrier(); \
    } while (0)

    if (wg < 16) {
        // ================= PRODUCER =================
        f16x8 wA[2][8], wP[2][8];
#pragma unroll
        for (int tt = 0; tt < 2; ++tt) {
            const int n = ncol + tt * 16 + q;
#pragma unroll
            for (int kb = 0; kb < 8; ++kb) {
                const int o = n * H_ + kb * 32 + g * 8;
                wA[tt][kb] = cvt8(*(const float4*)(Whh0 + o), *(const float4*)(Whh0 + o + 4));
                wP[tt][kb] = cvt8(*(const float4*)(Wih1 + o), *(const float4*)(Wih1 + o + 4));
            }
        }
        f32x4 bs1[2];
#pragma unroll
        for (int tt = 0; tt < 2; ++tt) {
            const int n = ncol + tt * 16 + g * 4;
            float4 x = *(const float4*)(bih1 + n);
            float4 y = *(const float4*)(bhh1 + n);
            bs1[tt][0] = x.x + y.x; bs1[tt][1] = x.y + y.y;
            bs1[tt][2] = x.z + y.z; bs1[tt][3] = x.w + y.w;
        }
        {   // h0_{-1}=0 into buf1 (read buffer of step 0): 512 thr x 16B = 8KB
            f32x4 z = {0.f, 0.f, 0.f, 0.f};
            *(f32x4*)(hb[1] + tid * 16) = z;
        }
        const int* idxr = idx + brow * S_;
        int* myflag = flags + wg * 8 + w;
        f16x4 xa[2], xb[2];
        {
            const size_t r0 = (size_t)idxr[0] * H_, r1 = (size_t)idxr[1] * H_;
#pragma unroll
            for (int tt = 0; tt < 2; ++tt) {
                xa[tt] = *(const f16x4*)(T + r0 + ncol + tt * 16 + g * 4);
                xb[tt] = *(const f16x4*)(T + r1 + ncol + tt * 16 + g * 4);
            }
        }
        int iA = idxr[2], iB = idxr[3];
        __syncthreads();

#define PBODY(XV, ID, RD, WR, T_) do {                                          \
        /* load all 8 B-fragments of h0_{T_-1}; keep live for A and P */        \
        f16x8 bf0 = FRD(0, RD), bf1 = FRD(1, RD), bf2 = FRD(2, RD),             \
              bf3 = FRD(3, RD), bf4 = FRD(4, RD), bf5 = FRD(5, RD),             \
              bf6 = FRD(6, RD), bf7 = FRD(7, RD);                               \
        f32x4 aL[2], aH[2];                                                     \
        _Pragma("unroll")                                                       \
        for (int tt = 0; tt < 2; ++tt) {                                        \
            aL[tt] = cvt4f(XV[tt]);                                             \
            aH[tt][0] = 0.f; aH[tt][1] = 0.f; aH[tt][2] = 0.f; aH[tt][3] = 0.f; \
        }                                                                       \
        {   /* reissue XV <- row (T_+2); reload ID <- idx[T_+4] */              \
            const size_t rr = (size_t)ID * H_;                                  \
            _Pragma("unroll")                                                   \
            for (int tt = 0; tt < 2; ++tt)                                      \
                XV[tt] = *(const f16x4*)(T + rr + ncol + tt * 16 + g * 4);      \
            const int t4 = ((T_) + 4 < S_) ? (T_) + 4 : S_ - 1;                 \
            ID = idxr[t4];                                                      \
        }                                                                       \
        /* A: two 4-deep chains per tt */                                       \
        _Pragma("unroll")                                                       \
        for (int tt = 0; tt < 2; ++tt) {                                        \
            aL[tt] = MFMA(wA[tt][0], bf0, aL[tt]);                              \
            aH[tt] = MFMA(wA[tt][4], bf4, aH[tt]);                              \
            aL[tt] = MFMA(wA[tt][1], bf1, aL[tt]);                              \
            aH[tt] = MFMA(wA[tt][5], bf5, aH[tt]);                              \
            aL[tt] = MFMA(wA[tt][2], bf2, aL[tt]);                              \
            aH[tt] = MFMA(wA[tt][6], bf6, aH[tt]);                              \
            aL[tt] = MFMA(wA[tt][3], bf3, aL[tt]);                              \
            aH[tt] = MFMA(wA[tt][7], bf7, aH[tt]);                              \
        }                                                                       \
        /* h0_T_ -> LDS immediately (critical path) */                          \
        _Pragma("unroll")                                                       \
        for (int tt = 0; tt < 2; ++tt) HWR(tt, WR) = tanh4(aL[tt], aH[tt]);     \
        /* P off the critical path: register-only on live fragments */          \
        f32x4 pL[2], pH[2];                                                     \
        _Pragma("unroll")                                                       \
        for (int tt = 0; tt < 2; ++tt) {                                        \
            pL[tt] = bs1[tt];                                                   \
            pH[tt][0] = 0.f; pH[tt][1] = 0.f; pH[tt][2] = 0.f; pH[tt][3] = 0.f; \
            pL[tt] = MFMA(wP[tt][0], bf0, pL[tt]);                              \
            pH[tt] = MFMA(wP[tt][4], bf4, pH[tt]);                              \
            pL[tt] = MFMA(wP[tt][1], bf1, pL[tt]);                              \
            pH[tt] = MFMA(wP[tt][5], bf5, pH[tt]);                              \
            pL[tt] = MFMA(wP[tt][2], bf2, pL[tt]);                              \
            pH[tt] = MFMA(wP[tt][6], bf6, pH[tt]);                              \
            pL[tt] = MFMA(wP[tt][3], bf3, pL[tt]);                              \
            pH[tt] = MFMA(wP[tt][7], bf7, pH[tt]);                              \
            *(f16x4*)(pbuf + (prow + (T_) - 1) * 256 + ncol + tt * 16 + g * 4)  \
                = pack4(pL[tt], pH[tt]);                                        \
        }                                                                       \
        if ((((T_) & 7) == 0) && lane == 0)                                     \
            __hip_atomic_store(myflag, (T_), __ATOMIC_RELEASE,                  \
                               __HIP_MEMORY_SCOPE_AGENT);                       \
        STEP_BAR();                                                             \
    } while (0)

        // peel t=0: A-chain only (h0_0 from zeros in buf1), reissue xa <- x_2
        {
            f16x8 bf0 = FRD(0, 1), bf1 = FRD(1, 1), bf2 = FRD(2, 1), bf3 = FRD(3, 1),
                  bf4 = FRD(4, 1), bf5 = FRD(5, 1), bf6 = FRD(6, 1), bf7 = FRD(7, 1);
            f32x4 aL[2], aH[2];
#pragma unroll
            for (int tt = 0; tt < 2; ++tt) {
                aL[tt] = cvt4f(xa[tt]);
                aH[tt][0] = 0.f; aH[tt][1] = 0.f; aH[tt][2] = 0.f; aH[tt][3] = 0.f;
            }
            {
                const size_t rr = (size_t)iA * H_;
#pragma unroll
                for (int tt = 0; tt < 2; ++tt)
                    xa[tt] = *(const f16x4*)(T + rr + ncol + tt * 16 + g * 4);
                iA = idxr[4];
            }
#pragma unroll
            for (int tt = 0; tt < 2; ++tt) {
                aL[tt] = MFMA(wA[tt][0], bf0, aL[tt]);
                aH[tt] = MFMA(wA[tt][4], bf4, aH[tt]);
                aL[tt] = MFMA(wA[tt][1], bf1, aL[tt]);
                aH[tt] = MFMA(wA[tt][5], bf5, aH[tt]);
                aL[tt] = MFMA(wA[tt][2], bf2, aL[tt]);
                aH[tt] = MFMA(wA[tt][6], bf6, aH[tt]);
                aL[tt] = MFMA(wA[tt][3], bf3, aL[tt]);
                aH[tt] = MFMA(wA[tt][7], bf7, aH[tt]);
                HWR(tt, 0) = tanh4(aL[tt], aH[tt]);
            }
            STEP_BAR();
        }
        // main: T_ = 1..510 in parity pairs, then 511
        for (int t = 1; t < 511; t += 2) {
            PBODY(xb, iB, 0, 1, t);
            PBODY(xa, iA, 1, 0, t + 1);
        }
        PBODY(xb, iB, 0, 1, 511);
        // peel T_=512: p_511 from h0_511 (in buf1)
        {
            f16x8 bf0 = FRD(0, 1), bf1 = FRD(1, 1), bf2 = FRD(2, 1), bf3 = FRD(3, 1),
                  bf4 = FRD(4, 1), bf5 = FRD(5, 1), bf6 = FRD(6, 1), bf7 = FRD(7, 1);
            f32x4 pL[2], pH[2];
#pragma unroll
            for (int tt = 0; tt < 2; ++tt) {
                pL[tt] = bs1[tt];
                pH[tt][0] = 0.f; pH[tt][1] = 0.f; pH[tt][2] = 0.f; pH[tt][3] = 0.f;
                pL[tt] = MFMA(wP[tt][0], bf0, pL[tt]);
                pH[tt] = MFMA(wP[tt][4], bf4, pH[tt]);
                pL[tt] = MFMA(wP[tt][1], bf1, pL[tt]);
                pH[tt] = MFMA(wP[tt][5], bf5, pH[tt]);
                pL[tt] = MFMA(wP[tt][2], bf2, pL[tt]);
                pH[tt] = MFMA(wP[tt][6], bf6, pH[tt]);
                pL[tt] = MFMA(wP[tt][3], bf3, pL[tt]);
                pH[tt] = MFMA(wP[tt][7], bf7, pH[tt]);
                *(f16x4*)(pbuf + (prow + 511) * 256 + ncol + tt * 16 + g * 4)
                    = pack4(pL[tt], pH[tt]);
            }
        }
        if (lane == 0)
            __hip_atomic_store(myflag, 512, __ATOMIC_RELEASE, __HIP_MEMORY_SCOPE_AGENT);
#undef PBODY
    } else {
        // ================= CONSUMER =================
        f16x8 wC[2][8];
#pragma unroll
        for (int tt = 0; tt < 2; ++tt) {
            const int n = ncol + tt * 16 + q;
#pragma unroll
            for (int kb = 0; kb < 8; ++kb) {
                const int o = n * H_ + kb * 32 + g * 8;
                wC[tt][kb] = cvt8(*(const float4*)(Whh1 + o), *(const float4*)(Whh1 + o + 4));
            }
        }
        {   f32x4 z = {0.f, 0.f, 0.f, 0.f}; *(f32x4*)(hb[1] + tid * 16) = z; }
        const int* fl = flags + pr * 8;
        __syncthreads();

#define SPIN(need) do {                                                         \
        int mn;                                                                 \
        do {                                                                    \
            mn = 0x7fffffff;                                                    \
            _Pragma("unroll")                                                   \
            for (int i = 0; i < 8; ++i) {                                       \
                int v = __hip_atomic_load(fl + i, __ATOMIC_RELAXED,             \
                                          __HIP_MEMORY_SCOPE_AGENT);            \
                mn = v < mn ? v : mn;                                           \
            }                                                                   \
        } while (mn < (need));                                                  \
        __builtin_amdgcn_fence(__ATOMIC_ACQUIRE, "agent");                      \
    } while (0)

#define CBODY(PV, RD, WR, T_) do {                                              \
        f16x8 cf0 = FRD(0, RD), cf1 = FRD(1, RD), cf2 = FRD(2, RD),             \
              cf3 = FRD(3, RD), cf4 = FRD(4, RD), cf5 = FRD(5, RD),             \
              cf6 = FRD(6, RD), cf7 = FRD(7, RD);                               \
        f32x4 aL[2], aH[2];                                                     \
        _Pragma("unroll")                                                       \
        for (int tt = 0; tt < 2; ++tt) {                                        \
            aL[tt] = cvt4f(PV[tt]);                                             \
            aH[tt][0] = 0.f; aH[tt][1] = 0.f; aH[tt][2] = 0.f; aH[tt][3] = 0.f; \
        }                                                                       \
        {                                                                       \
            const int tr = ((T_) + 2 < S_) ? (T_) + 2 : S_ - 1;                 \
            _Pragma("unroll")                                                   \
            for (int tt = 0; tt < 2; ++tt)                                      \
                PV[tt] = *(const f16x4*)(pbuf + (prow + tr) * 256 + ncol + tt * 16 + g * 4); \
        }                                                                       \
        _Pragma("unroll")                                                       \
        for (int tt = 0; tt < 2; ++tt) {                                        \
            aL[tt] = MFMA(wC[tt][0], cf0, aL[tt]);                              \
            aH[tt] = MFMA(wC[tt][4], cf4, aH[tt]);                              \
            aL[tt] = MFMA(wC[tt][1], cf1, aL[tt]);                              \
            aH[tt] = MFMA(wC[tt][5], cf5, aH[tt]);                              \
            aL[tt] = MFMA(wC[tt][2], cf2, aL[tt]);                              \
            aH[tt] = MFMA(wC[tt][6], cf6, aH[tt]);                              \
            aL[tt] = MFMA(wC[tt][3], cf3, aL[tt]);                              \
            aH[tt] = MFMA(wC[tt][7], cf7, aH[tt]);                              \
        }                                                                       \
        _Pragma("unroll")                                                       \
        for (int tt = 0; tt < 2; ++tt) {                                        \
            f16x4 hv = tanh4(aL[tt], aH[tt]);                                   \
            HWR(tt, WR) = hv;                                                   \
            if ((T_) == S_ - 1)                                                 \
                *(f16x4*)(h1out + (size_t)brow * H_ + ncol + tt * 16 + g * 4) = hv; \
        }                                                                       \
        STEP_BAR();                                                             \
    } while (0)

        f16x4 pa[2], pb[2];
        SPIN(6);
#pragma unroll
        for (int tt = 0; tt < 2; ++tt) {
            pa[tt] = *(const f16x4*)(pbuf + (prow + 0) * 256 + ncol + tt * 16 + g * 4);
            pb[tt] = *(const f16x4*)(pbuf + (prow + 1) * 256 + ncol + tt * 16 + g * 4);
        }
        for (int tb = 0; tb < 512; tb += 4) {
            if (tb) {
                const int need = (tb + 6 < 512) ? tb + 6 : 512;
                SPIN(need);
            }
            CBODY(pa, 1, 0, tb);
            CBODY(pb, 0, 1, tb + 1);
            CBODY(pa, 1, 0, tb + 2);
            CBODY(pb, 0, 1, tb + 3);
        }
#undef CBODY
#undef SPIN
    }
#undef FRD
#undef HWR
#undef STEP_BAR
}

// ---------------------------------------------------------------------------
// K3: out[b][v] = sum_k h1[b][k] * Wout[v][k] + bout[v].  fp32 out.
// ---------------------------------------------------------------------------
__global__ __launch_bounds__(512) void k_out(
    const f16* __restrict__ h1, const float* __restrict__ Wout,
    const float* __restrict__ bout, float* __restrict__ out)
{
    __shared__ char Hl[256 * 512];
    const int tid = threadIdx.x;
    {
        const int m = tid >> 1, half = tid & 1;
#pragma unroll
        for (int i = 0; i < 16; ++i) {
            const int blk = half * 16 + i;
            f16x8 v = *(const f16x8*)(h1 + m * H_ + blk * 8);
            *(f16x8*)(Hl + m * 512 + ((blk ^ (m & 7)) << 4)) = v;
        }
    }
    __syncthreads();
    const int lane = tid & 63, w = tid >> 6;
    const int q = lane & 15, g = lane >> 4;
    const int v0 = blockIdx.x * 80;
    f32x4 acc[5][2];
#pragma unroll
    for (int vt = 0; vt < 5; ++vt) {
        float4 bo = *(const float4*)(bout + v0 + vt * 16 + g * 4);
#pragma unroll
        for (int bt = 0; bt < 2; ++bt) {
            acc[vt][bt][0] = bo.x; acc[vt][bt][1] = bo.y;
            acc[vt][bt][2] = bo.z; acc[vt][bt][3] = bo.w;
        }
    }
#pragma unroll
    for (int kb = 0; kb < 8; ++kb) {
        f16x8 bf[2];
#pragma unroll
        for (int bt = 0; bt < 2; ++bt) {
            const int mrow = (w * 2 + bt) * 16 + q;
            bf[bt] = *(const f16x8*)(Hl + mrow * 512 + (((kb * 4 + g) ^ (mrow & 7)) << 4));
        }
#pragma unroll
        for (int vt = 0; vt < 5; ++vt) {
            const size_t vrow = v0 + vt * 16 + q;
            float4 a = *(const float4*)(Wout + vrow * H_ + kb * 32 + g * 8);
            float4 b = *(const float4*)(Wout + vrow * H_ + kb * 32 + g * 8 + 4);
            f16x8 af = cvt8(a, b);
#pragma unroll
            for (int bt = 0; bt < 2; ++bt)
                acc[vt][bt] = MFMA(af, bf[bt], acc[vt][bt]);
        }
    }
#pragma unroll
    for (int vt = 0; vt < 5; ++vt)
#pragma unroll
        for (int bt = 0; bt < 2; ++bt) {
            const int b = (w * 2 + bt) * 16 + q;
            const int v = v0 + vt * 16 + g * 4;
            float4 o = {acc[vt][bt][0], acc[vt][bt][1], acc[vt][bt][2], acc[vt][bt][3]};
            *(float4*)(out + (size_t)b * V_ + v) = o;
        }
}

extern "C" void kernel_launch(void* const* d_in, const int* in_sizes, int n_in,
                              void* d_out, int out_size, void* d_ws, size_t ws_size,
                              hipStream_t stream) {
    (void)in_sizes; (void)n_in; (void)out_size; (void)ws_size;
    const int*   batch = (const int*)  d_in[0];
    const float* feat  = (const float*)d_in[1];
    const float* Wih0  = (const float*)d_in[2];
    const float* Whh0  = (const float*)d_in[3];
    const float* bih0  = (const float*)d_in[4];
    const float* bhh0  = (const float*)d_in[5];
    const float* Wih1  = (const float*)d_in[6];
    const float* Whh1  = (const float*)d_in[7];
    const float* bih1  = (const float*)d_in[8];
    const float* bhh1  = (const float*)d_in[9];
    const float* Wout  = (const float*)d_in[10];
    const float* bout  = (const float*)d_in[11];
    float* out = (float*)d_out;

    f16* T     = (f16*)d_out;                             // 25.6MB scratch in d_out
    int* flags = (int*)((char*)d_out + 48000000);         // 512B, dead until k_out
    f16* pbuf  = (f16*)d_ws;                              // 67MB: p_t stream
    f16* h1out = (f16*)((char*)d_ws + (size_t)B_ * S_ * H_ * 2);  // 128KB

    k_init_flags<<<dim3(1), dim3(128), 0, stream>>>(flags);
    k_vocab_proj<<<dim3(V_ / 16), dim3(512), 0, stream>>>(feat, Wih0, bih0, bhh0, T);
    k_rnn_split<<<dim3(32), dim3(512), 0, stream>>>(T, batch, Whh0, Wih1, bih1, bhh1,
                                                    Whh1, pbuf, flags, h1out);
    k_out<<<dim3(625), dim3(512), 0, stream>>>(h1out, Wout, bout, out);
}